// Round 1
// baseline (20249.626 us; speedup 1.0000x reference)
//
#include <hip/hip_runtime.h>
#include <hip/hip_bf16.h>
#include <hip/hip_cooperative_groups.h>

namespace cg = cooperative_groups;

#define T_LEN  1024
#define BATCH  64
#define HDIM   512
#define G4     2048     // 4*H
#define TC     128      // timestep chunk
#define NCHUNK 8

typedef __attribute__((ext_vector_type(8))) short short8;
typedef __attribute__((ext_vector_type(4))) float f32x4;
typedef __hip_bfloat16 bf16;

__device__ __forceinline__ unsigned short bfbits(float f) {
    bf16 h = __float2bfloat16(f);
    return __builtin_bit_cast(unsigned short, h);
}

// ---------------------------------------------------------------------------
// Kernel 1: convert weights to bf16, combine biases.
// ---------------------------------------------------------------------------
__global__ void conv_weights(const float* __restrict__ wihf, const float* __restrict__ whhf,
                             const float* __restrict__ bihf, const float* __restrict__ bhhf,
                             const float* __restrict__ wihb, const float* __restrict__ whhb,
                             const float* __restrict__ bihb, const float* __restrict__ bhhb,
                             bf16* __restrict__ wih, bf16* __restrict__ whh,
                             float* __restrict__ bias)
{
    int i = blockIdx.x * 256 + threadIdx.x;      // 0 .. 2*2048*512-1
    const int n1 = G4 * HDIM;
    if (i < n1) {
        wih[i] = __float2bfloat16(wihf[i]);
        whh[i] = __float2bfloat16(whhf[i]);
    } else {
        int k = i - n1;
        wih[n1 + k] = __float2bfloat16(wihb[k]);
        whh[n1 + k] = __float2bfloat16(whhb[k]);
    }
    if (i < G4)          bias[i]      = bihf[i] + bhhf[i];
    else if (i < 2 * G4) bias[i]      = bihb[i - G4] + bhhb[i - G4];
}

// ---------------------------------------------------------------------------
// Kernel 2: initial h (bf16) and c (fp32) state.
// ---------------------------------------------------------------------------
__global__ void init_state(const float* __restrict__ h0f, const float* __restrict__ c0f,
                           const float* __restrict__ h0b, const float* __restrict__ c0b,
                           bf16* __restrict__ hbuf, float* __restrict__ cbuf)
{
    int i = blockIdx.x * 256 + threadIdx.x;      // 0..65535
    int d = i >> 15, r = i & 32767;
    const float* h0 = d ? h0b : h0f;
    const float* c0 = d ? c0b : c0f;
    // hbuf layout: [parity][dir][B*H]; h0 goes to parity 0
    hbuf[(0 * 2 + d) * (BATCH * HDIM) + r] = __float2bfloat16(h0[r]);
    cbuf[d * (BATCH * HDIM) + r] = c0[r];
}

// ---------------------------------------------------------------------------
// Kernel 3: input-projection GEMM for one chunk, both directions.
// G[dir][tt*64+b][j] = bias[dir][j] + sum_k x[src_t(t,b), b, k] * wih[dir][j][k]
// Tile 128x128, BK=64, 4 waves, mfma 16x16x32 bf16. Reg-staged LDS w/ XOR swizzle.
// ---------------------------------------------------------------------------
__global__ __launch_bounds__(256) void gemm_inproj(
        const float* __restrict__ x,        // [T][B][512] fp32
        const bf16*  __restrict__ wih,      // [2][2048][512] bf16
        const float* __restrict__ bias,     // [2][2048]
        const int*   __restrict__ lengths,  // [64]
        float*       __restrict__ G,        // [2][TC*B][2048]
        int t0)
{
    __shared__ __align__(16) char Abuf[128 * 64 * 2];
    __shared__ __align__(16) char Bbuf[128 * 64 * 2];
    __shared__ int Llds[BATCH];

    const int tid  = threadIdx.x;
    const int dir  = blockIdx.z;
    const int mblk = blockIdx.x;     // 0..63   (M = TC*B = 8192)
    const int nblk = blockIdx.y;     // 0..15   (N = 2048)

    if (tid < BATCH) Llds[tid] = lengths[tid];
    __syncthreads();

    const int lane = tid & 63;
    const int w    = tid >> 6;
    const int wm   = w >> 1, wn = w & 1;

    f32x4 acc[4][4];
#pragma unroll
    for (int i = 0; i < 4; i++)
#pragma unroll
        for (int j = 0; j < 4; j++) acc[i][j] = f32x4{0.f, 0.f, 0.f, 0.f};

    const bf16* wbase = wih + (size_t)dir * G4 * HDIM;

    for (int kk = 0; kk < 8; ++kk) {
        __syncthreads();
        // --- stage A (fp32 gather + convert) and B (bf16), 1024 16B-chunks each
#pragma unroll
        for (int i = 0; i < 4; i++) {
            int q = tid + i * 256;               // 0..1023
            int row = q >> 3, slot = q & 7;
            // A
            int mg = mblk * 128 + row;
            int t = t0 + (mg >> 6), b = mg & 63;
            int st = t;
            if (dir) { int L = Llds[b]; if (t < L) st = L - 1 - t; }
            const float* src = x + (size_t)(st * BATCH + b) * HDIM + kk * 64 + slot * 8;
            float4 f0 = *reinterpret_cast<const float4*>(src);
            float4 f1 = *reinterpret_cast<const float4*>(src + 4);
            union { unsigned short us[8]; uint4 v; } pk;
            pk.us[0] = bfbits(f0.x); pk.us[1] = bfbits(f0.y);
            pk.us[2] = bfbits(f0.z); pk.us[3] = bfbits(f0.w);
            pk.us[4] = bfbits(f1.x); pk.us[5] = bfbits(f1.y);
            pk.us[6] = bfbits(f1.z); pk.us[7] = bfbits(f1.w);
            *reinterpret_cast<uint4*>(&Abuf[(row * 128 + slot * 16) ^ ((row & 7) << 4)]) = pk.v;
            // B
            int jrow = nblk * 128 + row;
            uint4 wv = *reinterpret_cast<const uint4*>(wbase + (size_t)jrow * HDIM + kk * 64 + slot * 8);
            *reinterpret_cast<uint4*>(&Bbuf[(row * 128 + slot * 16) ^ ((row & 7) << 4)]) = wv;
        }
        __syncthreads();
        // --- compute
#pragma unroll
        for (int ks = 0; ks < 2; ++ks) {
            const int kbyte = ks * 64 + ((lane >> 4) * 16);
            short8 afr[4], bfr[4];
#pragma unroll
            for (int mi = 0; mi < 4; mi++) {
                int row = wm * 64 + mi * 16 + (lane & 15);
                afr[mi] = *reinterpret_cast<const short8*>(&Abuf[(row * 128 + kbyte) ^ ((row & 7) << 4)]);
            }
#pragma unroll
            for (int ni = 0; ni < 4; ni++) {
                int row = wn * 64 + ni * 16 + (lane & 15);
                bfr[ni] = *reinterpret_cast<const short8*>(&Bbuf[(row * 128 + kbyte) ^ ((row & 7) << 4)]);
            }
#pragma unroll
            for (int mi = 0; mi < 4; mi++)
#pragma unroll
                for (int ni = 0; ni < 4; ni++)
                    acc[mi][ni] = __builtin_amdgcn_mfma_f32_16x16x32_bf16(afr[mi], bfr[ni], acc[mi][ni], 0, 0, 0);
        }
    }
    // --- epilogue: add bias, store fp32
#pragma unroll
    for (int ni = 0; ni < 4; ni++) {
        int col = nblk * 128 + wn * 64 + ni * 16 + (lane & 15);
        float bs = bias[dir * G4 + col];
#pragma unroll
        for (int mi = 0; mi < 4; mi++) {
#pragma unroll
            for (int r = 0; r < 4; r++) {
                int row = mblk * 128 + wm * 64 + mi * 16 + (lane >> 4) * 4 + r;
                G[((size_t)dir * (TC * BATCH) + row) * G4 + col] = acc[mi][ni][r] + bs;
            }
        }
    }
}

// ---------------------------------------------------------------------------
// Kernel 4: persistent cooperative recurrence over one chunk of TC steps.
// 128 blocks x 512 threads. Blocks 0..63 = forward, 64..127 = backward.
// Block owns 8 hidden units (32 gate rows). w_hh slice resident in LDS,
// c state resident in registers, h broadcast via global double-buffer.
// ---------------------------------------------------------------------------
__global__ __launch_bounds__(512, 1) void lstm_chunk(
        const float* __restrict__ G,        // [2][TC*B][2048]
        const bf16*  __restrict__ whh,      // [2][2048][512] bf16
        bf16*        __restrict__ hbuf,     // [2][2][B][H] bf16
        float*       __restrict__ cbuf,     // [2][B][H] fp32
        const int*   __restrict__ lengths,  // [64]
        float*       __restrict__ out,      // [T][B][1024] fp32
        int t0)
{
    __shared__ __align__(16) char Wl[32 * HDIM * 2];    // 32KB, swizzled
    __shared__ __align__(16) char Hl[BATCH * HDIM * 2]; // 64KB, swizzled
    __shared__ float Gl[BATCH][33];                     // gates, padded

    const int tid  = threadIdx.x;
    const int dir  = (int)(blockIdx.x >> 6);
    const int blk  = (int)(blockIdx.x & 63);
    const int j0   = blk * 8;
    const int lane = tid & 63;
    const int w    = tid >> 6;          // 0..7
    const int wm   = w & 3;             // batch tile
    const int wn   = w >> 2;            // gate-col tile (0..1)

    // --- stage w_hh slice once: LDS row c -> whh[dir][(c>>3)*512 + j0 + (c&7)][:]
#pragma unroll
    for (int i = 0; i < 4; i++) {
        int q = tid + i * 512;          // 0..2047
        int c = q >> 6, s = q & 63;
        int grow = (c >> 3) * HDIM + j0 + (c & 7);
        uint4 v = *reinterpret_cast<const uint4*>(whh + (size_t)(dir * G4 + grow) * HDIM + s * 8);
        *reinterpret_cast<uint4*>(&Wl[(c * 1024 + s * 16) ^ ((c & 7) << 4)]) = v;
    }

    const int b_own = tid >> 3;         // 0..63
    const int jj    = tid & 7;
    float c_reg = cbuf[(dir * BATCH + b_own) * HDIM + j0 + jj];
    const int Lb = lengths[b_own];

    const int arow = wm * 16 + (lane & 15);    // batch row for A frag
    const int brow = wn * 16 + (lane & 15);    // gate-col row for B frag
    const int kb0  = (lane >> 4) * 16;         // byte offset within k

    cg::grid_group grid = cg::this_grid();
    __syncthreads();   // Wl ready

    for (int tt = 0; tt < TC; ++tt) {
        const int t = t0 + tt;
        const int p = t & 1;

        // prefetch this step's input-projection gates (independent of h)
        const float* Grow = G + ((size_t)dir * (TC * BATCH) + tt * BATCH + b_own) * G4;
        float pgi = Grow[j0 + jj];
        float pgf = Grow[HDIM + j0 + jj];
        float pgg = Grow[2 * HDIM + j0 + jj];
        float pgo = Grow[3 * HDIM + j0 + jj];

        // --- stage h_prev into swizzled LDS (64KB)
        const bf16* hsrc = hbuf + (size_t)(p * 2 + dir) * (BATCH * HDIM);
#pragma unroll
        for (int i = 0; i < 8; i++) {
            int q = tid + i * 512;       // 0..4095
            int b = q >> 6, s = q & 63;
            uint4 v = *reinterpret_cast<const uint4*>(hsrc + b * HDIM + s * 8);
            *reinterpret_cast<uint4*>(&Hl[(b * 1024 + s * 16) ^ ((b & 7) << 4)]) = v;
        }
        __syncthreads();

        // --- recurrent GEMM: gates[b][c] += sum_k h[b][k] * Wl[c][k]
        f32x4 acc = f32x4{0.f, 0.f, 0.f, 0.f};
#pragma unroll
        for (int ks = 0; ks < 16; ++ks) {
            int kbyte = ks * 64 + kb0;
            short8 a = *reinterpret_cast<const short8*>(&Hl[(arow * 1024 + kbyte) ^ ((arow & 7) << 4)]);
            short8 bb = *reinterpret_cast<const short8*>(&Wl[(brow * 1024 + kbyte) ^ ((brow & 7) << 4)]);
            acc = __builtin_amdgcn_mfma_f32_16x16x32_bf16(a, bb, acc, 0, 0, 0);
        }
        // scatter accumulator to Gl: col = lane&15 (+wn*16), row = (lane>>4)*4+r (+wm*16)
        {
            int col = wn * 16 + (lane & 15);
            int rbase = wm * 16 + (lane >> 4) * 4;
#pragma unroll
            for (int r = 0; r < 4; r++) Gl[rbase + r][col] = acc[r];
        }
        __syncthreads();

        // --- pointwise LSTM cell (thread owns (b_own, j0+jj))
        float gi = Gl[b_own][jj]       + pgi;
        float gf = Gl[b_own][8 + jj]   + pgf;
        float gg = Gl[b_own][16 + jj]  + pgg;
        float go = Gl[b_own][24 + jj]  + pgo;
        float iv = 1.f / (1.f + expf(-gi));
        float fv = 1.f / (1.f + expf(-gf));
        float gv = tanhf(gg);
        float ov = 1.f / (1.f + expf(-go));
        c_reg = fv * c_reg + iv * gv;
        float hv = ov * tanhf(c_reg);

        bf16* hdst = hbuf + (size_t)((p ^ 1) * 2 + dir) * (BATCH * HDIM);
        hdst[b_own * HDIM + j0 + jj] = __float2bfloat16(hv);

        int tout = t;
        if (dir) tout = (t < Lb) ? (Lb - 1 - t) : t;
        out[((size_t)tout * BATCH + b_own) * (2 * HDIM) + dir * HDIM + j0 + jj] = hv;

        grid.sync();
    }
    cbuf[(dir * BATCH + b_own) * HDIM + j0 + jj] = c_reg;
}

// ---------------------------------------------------------------------------
extern "C" void kernel_launch(void* const* d_in, const int* in_sizes, int n_in,
                              void* d_out, int out_size, void* d_ws, size_t ws_size,
                              hipStream_t stream)
{
    const float* x    = (const float*)d_in[0];
    const int* lengths = (const int*)d_in[1];
    const float* h0f  = (const float*)d_in[2];
    const float* c0f  = (const float*)d_in[3];
    const float* h0b  = (const float*)d_in[4];
    const float* c0b  = (const float*)d_in[5];
    const float* wihf = (const float*)d_in[6];
    const float* whhf = (const float*)d_in[7];
    const float* bihf = (const float*)d_in[8];
    const float* bhhf = (const float*)d_in[9];
    const float* wihb = (const float*)d_in[10];
    const float* whhb = (const float*)d_in[11];
    const float* bihb = (const float*)d_in[12];
    const float* bhhb = (const float*)d_in[13];
    float* out = (float*)d_out;

    char* ws = (char*)d_ws;
    bf16*  wih_bf = (bf16*)(ws);                           // 4 MB
    bf16*  whh_bf = (bf16*)(ws + (4u << 20));              // 4 MB
    float* bias   = (float*)(ws + (8u << 20));             // 16 KB
    bf16*  hbuf   = (bf16*)(ws + (9u << 20));              // 256 KB
    float* cbuf   = (float*)(ws + (10u << 20));            // 256 KB
    float* G      = (float*)(ws + (12u << 20));            // 134.2 MB
    // total ~146.8 MB

    conv_weights<<<dim3(2 * G4 * HDIM / 256), dim3(256), 0, stream>>>(
        wihf, whhf, bihf, bhhf, wihb, whhb, bihb, bhhb, wih_bf, whh_bf, bias);
    init_state<<<dim3(2 * BATCH * HDIM / 256), dim3(256), 0, stream>>>(
        h0f, c0f, h0b, c0b, hbuf, cbuf);

    for (int c = 0; c < NCHUNK; ++c) {
        int t0 = c * TC;
        gemm_inproj<<<dim3(TC * BATCH / 128, G4 / 128, 2), dim3(256), 0, stream>>>(
            x, wih_bf, bias, lengths, G, t0);
        void* args[] = { (void*)&G, (void*)&whh_bf, (void*)&hbuf, (void*)&cbuf,
                         (void*)&lengths, (void*)&out, (void*)&t0 };
        hipLaunchCooperativeKernel((const void*)lstm_chunk, dim3(128), dim3(512),
                                   args, 0, stream);
    }
}

// Round 2
// 8865.035 us; speedup vs baseline: 2.2842x; 2.2842x over previous
//
#include <hip/hip_runtime.h>
#include <hip/hip_bf16.h>

#define T_LEN  1024
#define BATCH  64
#define HDIM   512
#define G4     2048     // 4*H
#define TC     128      // timestep chunk
#define NCHUNK 8
#define NBLK_DIR 32     // blocks per direction team
#define UNITS  16       // hidden units per block

typedef __attribute__((ext_vector_type(8))) short short8;
typedef __attribute__((ext_vector_type(4))) float f32x4;
typedef __hip_bfloat16 bf16;

__device__ __forceinline__ unsigned short bfbits(float f) {
    bf16 h = __float2bfloat16(f);
    return __builtin_bit_cast(unsigned short, h);
}

// ---------------------------------------------------------------------------
// Kernel 1: convert weights to bf16, combine biases.
// ---------------------------------------------------------------------------
__global__ void conv_weights(const float* __restrict__ wihf, const float* __restrict__ whhf,
                             const float* __restrict__ bihf, const float* __restrict__ bhhf,
                             const float* __restrict__ wihb, const float* __restrict__ whhb,
                             const float* __restrict__ bihb, const float* __restrict__ bhhb,
                             bf16* __restrict__ wih, bf16* __restrict__ whh,
                             float* __restrict__ bias)
{
    int i = blockIdx.x * 256 + threadIdx.x;      // 0 .. 2*2048*512-1
    const int n1 = G4 * HDIM;
    if (i < n1) {
        wih[i] = __float2bfloat16(wihf[i]);
        whh[i] = __float2bfloat16(whhf[i]);
    } else {
        int k = i - n1;
        wih[n1 + k] = __float2bfloat16(wihb[k]);
        whh[n1 + k] = __float2bfloat16(whhb[k]);
    }
    if (i < G4)          bias[i]      = bihf[i] + bhhf[i];
    else if (i < 2 * G4) bias[i]      = bihb[i - G4] + bhhb[i - G4];
}

// ---------------------------------------------------------------------------
// Kernel 2: initial h (bf16) and c (fp32) state.
// ---------------------------------------------------------------------------
__global__ void init_state(const float* __restrict__ h0f, const float* __restrict__ c0f,
                           const float* __restrict__ h0b, const float* __restrict__ c0b,
                           bf16* __restrict__ hbuf, float* __restrict__ cbuf)
{
    int i = blockIdx.x * 256 + threadIdx.x;      // 0..65535
    int d = i >> 15, r = i & 32767;
    const float* h0 = d ? h0b : h0f;
    const float* c0 = d ? c0b : c0f;
    // hbuf layout: [parity][dir][B*H]; h0 goes to parity 0
    hbuf[(0 * 2 + d) * (BATCH * HDIM) + r] = __float2bfloat16(h0[r]);
    cbuf[d * (BATCH * HDIM) + r] = c0[r];
}

// ---------------------------------------------------------------------------
// Kernel 3: input-projection GEMM for one chunk, both directions.
// Also zeroes the barrier words for the following recurrence dispatch.
// ---------------------------------------------------------------------------
__global__ __launch_bounds__(256) void gemm_inproj(
        const float* __restrict__ x,        // [T][B][512] fp32
        const bf16*  __restrict__ wih,      // [2][2048][512] bf16
        const float* __restrict__ bias,     // [2][2048]
        const int*   __restrict__ lengths,  // [64]
        float*       __restrict__ G,        // [2][TC*B][2048]
        unsigned*    __restrict__ bar,      // [2*TC] barrier words
        int t0)
{
    __shared__ __align__(16) char Abuf[128 * 64 * 2];
    __shared__ __align__(16) char Bbuf[128 * 64 * 2];
    __shared__ int Llds[BATCH];

    const int tid  = threadIdx.x;
    const int dir  = blockIdx.z;
    const int mblk = blockIdx.x;     // 0..63   (M = TC*B = 8192)
    const int nblk = blockIdx.y;     // 0..15   (N = 2048)

    if (blockIdx.x == 0 && blockIdx.y == 0 && blockIdx.z == 0 && tid < 2 * TC)
        bar[tid] = 0;                // visible to next dispatch via kernel-end flush

    if (tid < BATCH) Llds[tid] = lengths[tid];
    __syncthreads();

    const int lane = tid & 63;
    const int w    = tid >> 6;
    const int wm   = w >> 1, wn = w & 1;

    f32x4 acc[4][4];
#pragma unroll
    for (int i = 0; i < 4; i++)
#pragma unroll
        for (int j = 0; j < 4; j++) acc[i][j] = f32x4{0.f, 0.f, 0.f, 0.f};

    const bf16* wbase = wih + (size_t)dir * G4 * HDIM;

    for (int kk = 0; kk < 8; ++kk) {
        __syncthreads();
#pragma unroll
        for (int i = 0; i < 4; i++) {
            int q = tid + i * 256;               // 0..1023
            int row = q >> 3, slot = q & 7;
            int mg = mblk * 128 + row;
            int t = t0 + (mg >> 6), b = mg & 63;
            int st = t;
            if (dir) { int L = Llds[b]; if (t < L) st = L - 1 - t; }
            const float* src = x + (size_t)(st * BATCH + b) * HDIM + kk * 64 + slot * 8;
            float4 f0 = *reinterpret_cast<const float4*>(src);
            float4 f1 = *reinterpret_cast<const float4*>(src + 4);
            union { unsigned short us[8]; uint4 v; } pk;
            pk.us[0] = bfbits(f0.x); pk.us[1] = bfbits(f0.y);
            pk.us[2] = bfbits(f0.z); pk.us[3] = bfbits(f0.w);
            pk.us[4] = bfbits(f1.x); pk.us[5] = bfbits(f1.y);
            pk.us[6] = bfbits(f1.z); pk.us[7] = bfbits(f1.w);
            *reinterpret_cast<uint4*>(&Abuf[(row * 128 + slot * 16) ^ ((row & 7) << 4)]) = pk.v;
            int jrow = nblk * 128 + row;
            uint4 wv = *reinterpret_cast<const uint4*>(wbase + (size_t)jrow * HDIM + kk * 64 + slot * 8);
            *reinterpret_cast<uint4*>(&Bbuf[(row * 128 + slot * 16) ^ ((row & 7) << 4)]) = wv;
        }
        __syncthreads();
#pragma unroll
        for (int ks = 0; ks < 2; ++ks) {
            const int kbyte = ks * 64 + ((lane >> 4) * 16);
            short8 afr[4], bfr[4];
#pragma unroll
            for (int mi = 0; mi < 4; mi++) {
                int row = wm * 64 + mi * 16 + (lane & 15);
                afr[mi] = *reinterpret_cast<const short8*>(&Abuf[(row * 128 + kbyte) ^ ((row & 7) << 4)]);
            }
#pragma unroll
            for (int ni = 0; ni < 4; ni++) {
                int row = wn * 64 + ni * 16 + (lane & 15);
                bfr[ni] = *reinterpret_cast<const short8*>(&Bbuf[(row * 128 + kbyte) ^ ((row & 7) << 4)]);
            }
#pragma unroll
            for (int mi = 0; mi < 4; mi++)
#pragma unroll
                for (int ni = 0; ni < 4; ni++)
                    acc[mi][ni] = __builtin_amdgcn_mfma_f32_16x16x32_bf16(afr[mi], bfr[ni], acc[mi][ni], 0, 0, 0);
        }
    }
#pragma unroll
    for (int ni = 0; ni < 4; ni++) {
        int col = nblk * 128 + wn * 64 + ni * 16 + (lane & 15);
        float bs = bias[dir * G4 + col];
#pragma unroll
        for (int mi = 0; mi < 4; mi++) {
#pragma unroll
            for (int r = 0; r < 4; r++) {
                int row = mblk * 128 + wm * 64 + mi * 16 + (lane >> 4) * 4 + r;
                G[((size_t)dir * (TC * BATCH) + row) * G4 + col] = acc[mi][ni][r] + bs;
            }
        }
    }
}

// ---------------------------------------------------------------------------
// Kernel 4: recurrence, two independent 32-block teams (fwd / bwd).
// Block owns 16 hidden units (64 gate rows, 64KB w_hh slice in LDS).
// h exchanged via IF$ with system-scope atomics; per-step counter barrier.
// ---------------------------------------------------------------------------
__global__ __launch_bounds__(512, 1) void lstm_team(
        const float* __restrict__ G,        // [2][TC*B][2048]
        const bf16*  __restrict__ whh,      // [2][2048][512] bf16
        bf16*        __restrict__ hbuf,     // [2 parity][2 dir][B][H] bf16
        float*       __restrict__ cbuf,     // [2][B][H] fp32
        const int*   __restrict__ lengths,  // [64]
        float*       __restrict__ out,      // [T][B][1024] fp32
        unsigned*    __restrict__ bar,      // [2*TC], zeroed by gemm dispatch
        int t0)
{
    __shared__ __align__(16) char Wl[64 * HDIM * 2];    // 64KB, swizzled
    __shared__ __align__(16) char Hl[BATCH * HDIM * 2]; // 64KB, swizzled
    __shared__ float Gl[BATCH][68];                     // 17.4KB, conflict-free

    const int tid  = threadIdx.x;
    const int dir  = (int)(blockIdx.x >> 5);
    const int blk  = (int)(blockIdx.x & 31);
    const int j0   = blk * UNITS;
    const int lane = tid & 63;
    const int w    = tid >> 6;          // 0..7
    const int wm   = w & 3;             // batch tile (4 x 16 = 64)
    const int wn   = w >> 2;            // gate-col tile (2 x 32 = 64)

    // --- stage w_hh slice once: LDS row c (0..63) = gate (c>>4), unit j0+(c&15)
#pragma unroll
    for (int i = 0; i < 8; i++) {
        int q = tid + i * 512;          // 0..4095
        int c = q >> 6, s = q & 63;
        int grow = (c >> 4) * HDIM + j0 + (c & 15);
        uint4 v = *reinterpret_cast<const uint4*>(whh + (size_t)(dir * G4 + grow) * HDIM + s * 8);
        *reinterpret_cast<uint4*>(&Wl[(c * 1024 + s * 16) ^ ((c & 7) << 4)]) = v;
    }

    const int b_own = tid >> 3;         // 0..63
    const int jj    = tid & 7;          // cells (b_own, jj) and (b_own, jj+8)
    float c0r = cbuf[(dir * BATCH + b_own) * HDIM + j0 + jj];
    float c1r = cbuf[(dir * BATCH + b_own) * HDIM + j0 + jj + 8];
    const int Lb = lengths[b_own];

    const int arow  = wm * 16 + (lane & 15);
    const int brow0 = (wn * 2) * 16 + (lane & 15);
    const int brow1 = (wn * 2 + 1) * 16 + (lane & 15);
    const int kb0   = (lane >> 4) * 16;

    // prefetch G gates for tt = 0
    float pg[8];
    {
        const float* Gr = G + ((size_t)dir * (TC * BATCH) + b_own) * G4 + j0;
#pragma unroll
        for (int g = 0; g < 4; g++) {
            pg[g]     = Gr[g * HDIM + jj];
            pg[4 + g] = Gr[g * HDIM + jj + 8];
        }
    }

    __syncthreads();   // Wl ready

    for (int tt = 0; tt < TC; ++tt) {
        const int t = t0 + tt;
        const int p = t & 1;

        // --- stage h_prev: system-scope loads (bypass stale per-XCD L2)
        const unsigned long long* hs = reinterpret_cast<const unsigned long long*>(
                hbuf + (size_t)(p * 2 + dir) * (BATCH * HDIM));
#pragma unroll
        for (int i = 0; i < 16; i++) {
            int q = tid + i * 512;               // u64 index 0..8191
            unsigned long long v = __hip_atomic_load(hs + q, __ATOMIC_RELAXED, __HIP_MEMORY_SCOPE_SYSTEM);
            int byte = q * 8;
            int b = byte >> 10, s8 = byte & 1023;
            *reinterpret_cast<unsigned long long*>(&Hl[(b * 1024 + s8) ^ ((b & 7) << 4)]) = v;
        }

        // --- prefetch next step's G (plain cached loads, hides HBM latency)
        float pn[8];
        {
            int ttn = (tt + 1 < TC) ? (tt + 1) : tt;
            const float* Gr = G + ((size_t)dir * (TC * BATCH) + ttn * BATCH + b_own) * G4 + j0;
#pragma unroll
            for (int g = 0; g < 4; g++) {
                pn[g]     = Gr[g * HDIM + jj];
                pn[4 + g] = Gr[g * HDIM + jj + 8];
            }
        }

        __syncthreads();  // Hl ready

        // --- recurrent GEMM: Gl[b][c] = sum_k h[b][k] * Wl[c][k]
        f32x4 acc0 = f32x4{0.f, 0.f, 0.f, 0.f};
        f32x4 acc1 = f32x4{0.f, 0.f, 0.f, 0.f};
#pragma unroll
        for (int ks = 0; ks < 16; ++ks) {
            int kbyte = ks * 64 + kb0;
            short8 a  = *reinterpret_cast<const short8*>(&Hl[(arow * 1024 + kbyte) ^ ((arow & 7) << 4)]);
            short8 b0 = *reinterpret_cast<const short8*>(&Wl[(brow0 * 1024 + kbyte) ^ ((brow0 & 7) << 4)]);
            short8 b1 = *reinterpret_cast<const short8*>(&Wl[(brow1 * 1024 + kbyte) ^ ((brow1 & 7) << 4)]);
            acc0 = __builtin_amdgcn_mfma_f32_16x16x32_bf16(a, b0, acc0, 0, 0, 0);
            acc1 = __builtin_amdgcn_mfma_f32_16x16x32_bf16(a, b1, acc1, 0, 0, 0);
        }
        {
            int col0 = wn * 32 + (lane & 15);
            int rb   = wm * 16 + (lane >> 4) * 4;
#pragma unroll
            for (int r = 0; r < 4; r++) {
                Gl[rb + r][col0]      = acc0[r];
                Gl[rb + r][col0 + 16] = acc1[r];
            }
        }
        __syncthreads();

        // --- pointwise LSTM cell, 2 cells per thread
        float gi0 = Gl[b_own][jj]          + pg[0];
        float gf0 = Gl[b_own][16 + jj]     + pg[1];
        float gg0 = Gl[b_own][32 + jj]     + pg[2];
        float go0 = Gl[b_own][48 + jj]     + pg[3];
        float gi1 = Gl[b_own][jj + 8]      + pg[4];
        float gf1 = Gl[b_own][16 + jj + 8] + pg[5];
        float gg1 = Gl[b_own][32 + jj + 8] + pg[6];
        float go1 = Gl[b_own][48 + jj + 8] + pg[7];

        float iv0 = 1.f / (1.f + expf(-gi0));
        float fv0 = 1.f / (1.f + expf(-gf0));
        float gv0 = tanhf(gg0);
        float ov0 = 1.f / (1.f + expf(-go0));
        c0r = fv0 * c0r + iv0 * gv0;
        float hv0 = ov0 * tanhf(c0r);

        float iv1 = 1.f / (1.f + expf(-gi1));
        float fv1 = 1.f / (1.f + expf(-gf1));
        float gv1 = tanhf(gg1);
        float ov1 = 1.f / (1.f + expf(-go1));
        c1r = fv1 * c1r + iv1 * gv1;
        float hv1 = ov1 * tanhf(c1r);

        // --- h store: pack pairs, system-scope dword write-through to IF$
        unsigned lo0 = (unsigned)bfbits(hv0);
        unsigned lo1 = (unsigned)bfbits(hv1);
        unsigned hi0 = (unsigned)__shfl_down((int)lo0, 1);
        unsigned hi1 = (unsigned)__shfl_down((int)lo1, 1);
        if ((jj & 1) == 0) {
            unsigned* hd = reinterpret_cast<unsigned*>(
                    hbuf + (size_t)((p ^ 1) * 2 + dir) * (BATCH * HDIM));
            int base = b_own * 256 + ((j0 + jj) >> 1);
            __hip_atomic_store(hd + base,     lo0 | (hi0 << 16), __ATOMIC_RELAXED, __HIP_MEMORY_SCOPE_SYSTEM);
            __hip_atomic_store(hd + base + 4, lo1 | (hi1 << 16), __ATOMIC_RELAXED, __HIP_MEMORY_SCOPE_SYSTEM);
        }

        // --- output (plain stores; flushed at kernel end)
        int tout = t;
        if (dir) tout = (t < Lb) ? (Lb - 1 - t) : t;
        float* od = out + ((size_t)tout * BATCH + b_own) * (2 * HDIM) + dir * HDIM + j0 + jj;
        od[0] = hv0;
        od[8] = hv1;

        // --- team barrier (skip after last step; dispatch boundary covers it)
        if (tt < TC - 1) {
            __syncthreads();   // drains vmcnt(0): sys h-stores are at IF$
            if (tid == 0) {
                unsigned* bw = bar + dir * TC + tt;
                __hip_atomic_fetch_add(bw, 1u, __ATOMIC_RELAXED, __HIP_MEMORY_SCOPE_SYSTEM);
                while (__hip_atomic_load(bw, __ATOMIC_RELAXED, __HIP_MEMORY_SCOPE_SYSTEM) < (unsigned)NBLK_DIR) { }
            }
            __syncthreads();   // release block
        }

#pragma unroll
        for (int g = 0; g < 8; g++) pg[g] = pn[g];
    }

    cbuf[(dir * BATCH + b_own) * HDIM + j0 + jj]     = c0r;
    cbuf[(dir * BATCH + b_own) * HDIM + j0 + jj + 8] = c1r;
}

// ---------------------------------------------------------------------------
extern "C" void kernel_launch(void* const* d_in, const int* in_sizes, int n_in,
                              void* d_out, int out_size, void* d_ws, size_t ws_size,
                              hipStream_t stream)
{
    const float* x    = (const float*)d_in[0];
    const int* lengths = (const int*)d_in[1];
    const float* h0f  = (const float*)d_in[2];
    const float* c0f  = (const float*)d_in[3];
    const float* h0b  = (const float*)d_in[4];
    const float* c0b  = (const float*)d_in[5];
    const float* wihf = (const float*)d_in[6];
    const float* whhf = (const float*)d_in[7];
    const float* bihf = (const float*)d_in[8];
    const float* bhhf = (const float*)d_in[9];
    const float* wihb = (const float*)d_in[10];
    const float* whhb = (const float*)d_in[11];
    const float* bihb = (const float*)d_in[12];
    const float* bhhb = (const float*)d_in[13];
    float* out = (float*)d_out;

    char* ws = (char*)d_ws;
    bf16*     wih_bf = (bf16*)(ws);                        // 4 MB
    bf16*     whh_bf = (bf16*)(ws + (4u << 20));           // 4 MB
    float*    bias   = (float*)(ws + (8u << 20));          // 16 KB
    bf16*     hbuf   = (bf16*)(ws + (9u << 20));           // 256 KB
    float*    cbuf   = (float*)(ws + (10u << 20));         // 256 KB
    unsigned* bar    = (unsigned*)(ws + (11u << 20));      // 1 KB
    float*    G      = (float*)(ws + (12u << 20));         // 134.2 MB

    conv_weights<<<dim3(2 * G4 * HDIM / 256), dim3(256), 0, stream>>>(
        wihf, whhf, bihf, bhhf, wihb, whhb, bihb, bhhb, wih_bf, whh_bf, bias);
    init_state<<<dim3(2 * BATCH * HDIM / 256), dim3(256), 0, stream>>>(
        h0f, c0f, h0b, c0b, hbuf, cbuf);

    for (int c = 0; c < NCHUNK; ++c) {
        int t0 = c * TC;
        gemm_inproj<<<dim3(TC * BATCH / 128, G4 / 128, 2), dim3(256), 0, stream>>>(
            x, wih_bf, bias, lengths, G, bar, t0);
        lstm_team<<<dim3(2 * NBLK_DIR), dim3(512), 0, stream>>>(
            G, whh_bf, hbuf, cbuf, lengths, out, bar, t0);
    }
}

// Round 4
// 2488.352 us; speedup vs baseline: 8.1378x; 3.5626x over previous
//
#include <hip/hip_runtime.h>
#include <hip/hip_bf16.h>

#define T_LEN  1024
#define BATCH  64
#define HDIM   512
#define G4     2048

typedef __attribute__((ext_vector_type(8))) short short8;
typedef __attribute__((ext_vector_type(4))) float f32x4;
typedef __attribute__((ext_vector_type(4))) unsigned int u32x4;
typedef __hip_bfloat16 bf16;

__device__ __forceinline__ unsigned short bfbits(float f) {
    bf16 h = __float2bfloat16(f);
    return __builtin_bit_cast(unsigned short, h);
}
__device__ __forceinline__ float fsigmoid(float x) { return 1.f / (1.f + __expf(-x)); }
__device__ __forceinline__ float ftanh(float x)    { return 2.f / (1.f + __expf(-2.f * x)) - 1.f; }

// ---------------------------------------------------------------------------
// Kernel 1: convert weights to bf16, combine biases.
// ---------------------------------------------------------------------------
__global__ void conv_weights(const float* __restrict__ wihf, const float* __restrict__ whhf,
                             const float* __restrict__ bihf, const float* __restrict__ bhhf,
                             const float* __restrict__ wihb, const float* __restrict__ whhb,
                             const float* __restrict__ bihb, const float* __restrict__ bhhb,
                             bf16* __restrict__ wih, bf16* __restrict__ whh,
                             float* __restrict__ bias)
{
    int i = blockIdx.x * 256 + threadIdx.x;      // 0 .. 2*2048*512-1
    const int n1 = G4 * HDIM;
    if (i < n1) {
        wih[i] = __float2bfloat16(wihf[i]);
        whh[i] = __float2bfloat16(whhf[i]);
    } else {
        int k = i - n1;
        wih[n1 + k] = __float2bfloat16(wihb[k]);
        whh[n1 + k] = __float2bfloat16(whhb[k]);
    }
    if (i < G4)          bias[i] = bihf[i] + bhhf[i];
    else if (i < 2 * G4) bias[i] = bihb[i - G4] + bhhb[i - G4];
}

// ---------------------------------------------------------------------------
// Kernel 2: convert x to bf16 (identical content every replay -> stale-safe)
// ---------------------------------------------------------------------------
__global__ void conv_x(const float* __restrict__ x, bf16* __restrict__ xb)
{
    size_t i = (size_t)blockIdx.x * 256 + threadIdx.x;   // octet id
    const float* s = x + i * 8;
    float4 a = *reinterpret_cast<const float4*>(s);
    float4 b = *reinterpret_cast<const float4*>(s + 4);
    union { unsigned short us[8]; u32x4 v; } p;
    p.us[0] = bfbits(a.x); p.us[1] = bfbits(a.y); p.us[2] = bfbits(a.z); p.us[3] = bfbits(a.w);
    p.us[4] = bfbits(b.x); p.us[5] = bfbits(b.y); p.us[6] = bfbits(b.z); p.us[7] = bfbits(b.w);
    *reinterpret_cast<u32x4*>(xb + i * 8) = p.v;
}

// ---------------------------------------------------------------------------
// Kernel 3: initial h (bf16, parity 0) and c (fp32); zero flags/xcd/abort.
// ---------------------------------------------------------------------------
__global__ void init_state(const float* __restrict__ h0f, const float* __restrict__ c0f,
                           const float* __restrict__ h0b, const float* __restrict__ c0b,
                           bf16* __restrict__ hbuf, float* __restrict__ cbuf,
                           unsigned* __restrict__ flags, unsigned* __restrict__ xcdarr,
                           unsigned* __restrict__ abortw)
{
    int i = blockIdx.x * 256 + threadIdx.x;      // 0..65535
    int d = i >> 15, r = i & 32767;
    const float* h0 = d ? h0b : h0f;
    const float* c0 = d ? c0b : c0f;
    hbuf[(0 * 2 + d) * (BATCH * HDIM) + r] = __float2bfloat16(h0[r]);
    cbuf[d * (BATCH * HDIM) + r] = c0[r];
    if (blockIdx.x == 0) {
        flags[threadIdx.x]  = 0;
        xcdarr[threadIdx.x] = 0;
        if (threadIdx.x == 0) *abortw = 0;
    }
}

// ---------------------------------------------------------------------------
// Kernel 4: full 1024-step bidirectional recurrence, fused input projection.
// 256 blocks x 256 threads. 8 teams = 2 dirs x 4 batch-quarters, 32 blocks.
// Fast path (team verified XCD-local): h + flags through the team L2.
// Replay-safety: every cross-dispatch read is system-scope (cbuf, h@t=0),
// and team flag words are re-zeroed THROUGH THE TEAM L2 before use, ordered
// by a two-phase handshake; fast/fallback decision made once by rank 0.
// ---------------------------------------------------------------------------
__global__ __launch_bounds__(256, 1) void lstm_full(
        const bf16* __restrict__ xb,        // [T][B][512] bf16
        const bf16* __restrict__ wih,       // [2][2048][512] bf16
        const bf16* __restrict__ whh,       // [2][2048][512] bf16
        const float* __restrict__ bias,     // [2][2048]
        const int*  __restrict__ lengths,   // [64]
        bf16*       __restrict__ hbuf,      // [2 parity][2 dir][B][H] bf16
        float*      __restrict__ cbuf,      // [2][B][H] fp32
        float*      __restrict__ out,       // [T][B][1024] fp32
        unsigned*   __restrict__ flags,     // [8*32]
        unsigned*   __restrict__ xcdarr,    // [256]
        unsigned*   __restrict__ abortw)    // [1]
{
    __shared__ __align__(16) char Wl[64 * 2048];   // 128KB: [W_ih | W_hh] slice
    __shared__ __align__(16) char Al[16 * 1024];   // 16KB:  x_t then h_t (reused)
    __shared__ float Gl[16][68];                   // gate exchange
    __shared__ int ok_sh;

    const int tid  = threadIdx.x;
    const int team = (int)blockIdx.x & 7;
    const int rank = (int)blockIdx.x >> 3;
    const int dir  = team >> 2;
    const int b0   = (team & 3) * 16;
    const int u0   = rank * 16;
    const int lane = tid & 63;
    const int w    = tid >> 6;

    // phase 1: publish my XCD id (low 5 bits; value 1..16)
    if (tid == 0) {
        unsigned xcc;
        asm volatile("s_getreg_b32 %0, hwreg(20, 0, 32)" : "=s"(xcc));
        __hip_atomic_store(&xcdarr[blockIdx.x], (xcc & 0xFu) + 1u,
                           __ATOMIC_RELAXED, __HIP_MEMORY_SCOPE_SYSTEM);
    }

    // stage W slice: row c (0..63) = gate (c>>4), unit u0+(c&15); [ih | hh]
    {
        const bf16* wihd = wih + (size_t)dir * G4 * HDIM;
        const bf16* whhd = whh + (size_t)dir * G4 * HDIM;
#pragma unroll
        for (int i = 0; i < 32; i++) {
            int q = tid + i * 256;               // 0..8191 16B-slots
            int c = q >> 7, s = q & 127;
            int grow = (c >> 4) * HDIM + u0 + (c & 15);
            const bf16* src = (s < 64) ? (wihd + (size_t)grow * HDIM + s * 8)
                                       : (whhd + (size_t)grow * HDIM + (s - 64) * 8);
            u32x4 v = *reinterpret_cast<const u32x4*>(src);
            *reinterpret_cast<u32x4*>(&Wl[(c * 2048 + s * 16) ^ ((c & 7) << 4)]) = v;
        }
    }

    // phase 2: rank 0 verifies placement, zeroes team flags via team L2,
    // publishes the team-uniform decision; others wait for it.
    if (rank == 0) {
        if (w == 0) {
            int idx = (lane < 32) ? (team + lane * 8) : ((team ^ 1) + (lane - 32) * 8);
            const unsigned* p = xcdarr + idx;
            unsigned v = 0, cnt = 0; int timeout = 0;
            for (;;) {
                v = __hip_atomic_load(p, __ATOMIC_RELAXED, __HIP_MEMORY_SCOPE_SYSTEM);
                if (__all((int)((v & 31u) != 0u))) break;
                if (++cnt > (1u << 20)) { timeout = 1; break; }
            }
            unsigned my = (unsigned)__shfl((int)(v & 31u), 0);  // own slot at lane 0
            int ok = (!timeout) &&
                     __all(lane < 32 ? (int)((v & 31u) == my) : (int)((v & 31u) != my));
            if (ok && lane < 32)   // zero flag words IN THE TEAM L2 (plain store)
                __hip_atomic_store(&flags[team * 32 + lane], 0u,
                                   __ATOMIC_RELAXED, __HIP_MEMORY_SCOPE_WORKGROUP);
            asm volatile("s_waitcnt vmcnt(0)" ::: "memory");   // zeros at L2
            if (lane == 0) {
                unsigned pub = my | 32u | (ok ? 64u : 0u);
                __hip_atomic_store(&xcdarr[blockIdx.x], pub,
                                   __ATOMIC_RELAXED, __HIP_MEMORY_SCOPE_SYSTEM);
                ok_sh = ok;
            }
        }
    } else {
        if (tid == 0) {
            const unsigned* p = xcdarr + team;   // rank 0's slot
            unsigned v;
            do {
                v = __hip_atomic_load(p, __ATOMIC_RELAXED, __HIP_MEMORY_SCOPE_SYSTEM);
            } while (!(v & 32u));
            ok_sh = (int)((v >> 6) & 1u);
        }
    }

    const int bb = tid >> 4;                 // local batch 0..15
    const int uu = tid & 15;                 // local unit  0..15
    const int b_glob = b0 + bb;
    const int Lb = lengths[b_glob];
    // cbuf crosses dispatches with differing values -> system scope (stale-safe)
    float c_reg = __hip_atomic_load(&cbuf[((size_t)dir * BATCH + b_glob) * HDIM + u0 + uu],
                                    __ATOMIC_RELAXED, __HIP_MEMORY_SCOPE_SYSTEM);
    float bias_r[4];
#pragma unroll
    for (int g = 0; g < 4; g++)
        bias_r[g] = bias[dir * G4 + g * HDIM + u0 + uu];
    int Lw[4];
#pragma unroll
    for (int i = 0; i < 4; i++) Lw[i] = lengths[b0 + i * 4 + w];

    const int arow  = lane & 15;
    const int axor  = (arow & 7) << 4;
    const int abase = arow * 1024;
    const int brow  = w * 16 + (lane & 15);
    const int bxor  = (brow & 7) << 4;
    const int bbase = brow * 2048;
    const int kbhi  = (lane >> 4) * 16;

    unsigned* flagw = flags + team * 32 + rank;
    const unsigned* pollp = flags + team * 32 + (lane & 31);

    __syncthreads();                         // Wl staged + ok_sh valid
    const bool fast = (ok_sh != 0);

    for (int t = 0; t < T_LEN; ++t) {
        const int p = t & 1;

        // 1. stage x_t (independent of h; off critical path)
#pragma unroll
        for (int i = 0; i < 4; i++) {
            int row = i * 4 + w;
            int st = t;
            if (dir) { int L = Lw[i]; st = (t < L) ? (L - 1 - t) : t; }
            u32x4 v = *reinterpret_cast<const u32x4*>(
                xb + ((size_t)st * BATCH + b0 + row) * HDIM + lane * 8);
            *reinterpret_cast<u32x4*>(&Al[(row * 1024 + lane * 16) ^ ((row & 7) << 4)]) = v;
        }
        __syncthreads();

        // 2. MFMA x-pass (W_ih half)
        f32x4 acc = f32x4{0.f, 0.f, 0.f, 0.f};
#pragma unroll
        for (int ks = 0; ks < 16; ++ks) {
            int kb = ks * 64 + kbhi;
            short8 a = *reinterpret_cast<const short8*>(&Al[(abase + kb) ^ axor]);
            short8 b = *reinterpret_cast<const short8*>(&Wl[(bbase + kb) ^ bxor]);
            acc = __builtin_amdgcn_mfma_f32_16x16x32_bf16(a, b, acc, 0, 0, 0);
        }

        // 3. wait for h_t (flags >= t); trivially passes at t=0
        if (w == 0 && t > 0) {
            unsigned token = (unsigned)t, v, cnt = 0;
            if (fast) {
                for (;;) {
                    asm volatile("global_load_dword %0, %1, off sc0\n\ts_waitcnt vmcnt(0)"
                                 : "=v"(v) : "v"(pollp) : "memory");
                    if (__all((int)(v >= token))) break;
                    if (((++cnt) & 4095u) == 0) {
                        if (__hip_atomic_load(abortw, __ATOMIC_RELAXED, __HIP_MEMORY_SCOPE_SYSTEM)) break;
                        if (cnt > (1u << 22)) {
                            __hip_atomic_store(abortw, 1u, __ATOMIC_RELAXED, __HIP_MEMORY_SCOPE_SYSTEM);
                            break;
                        }
                    }
                }
            } else {
                for (;;) {
                    v = __hip_atomic_load(pollp, __ATOMIC_RELAXED, __HIP_MEMORY_SCOPE_SYSTEM);
                    if (__all((int)(v >= token))) break;
                    if (((++cnt) & 4095u) == 0) {
                        if (__hip_atomic_load(abortw, __ATOMIC_RELAXED, __HIP_MEMORY_SCOPE_SYSTEM)) break;
                        if (cnt > (1u << 22)) {
                            __hip_atomic_store(abortw, 1u, __ATOMIC_RELAXED, __HIP_MEMORY_SCOPE_SYSTEM);
                            break;
                        }
                    }
                }
            }
        }
        __syncthreads();   // poll done + MFMA-x reads of Al complete

        // 4. load h_t into Al. t=0 crosses the dispatch boundary (init_state
        //    wrote h0) -> system scope; t>0 is this-replay team-L2 data.
        {
            const bf16* hb = hbuf + ((size_t)(p * 2 + dir) * BATCH + b0) * HDIM;
            if (fast && t > 0) {
                u32x4 h4[4];
#pragma unroll
                for (int i = 0; i < 4; i++) {
                    int row = i * 4 + w;
                    const bf16* hp = hb + (size_t)row * HDIM + lane * 8;
                    asm volatile("global_load_dwordx4 %0, %1, off sc0"
                                 : "=v"(h4[i]) : "v"(hp) : "memory");
                }
                asm volatile("s_waitcnt vmcnt(0)" ::: "memory");
#pragma unroll
                for (int i = 0; i < 4; i++) {
                    int row = i * 4 + w;
                    *reinterpret_cast<u32x4*>(&Al[(row * 1024 + lane * 16) ^ ((row & 7) << 4)]) = h4[i];
                }
            } else {
#pragma unroll
                for (int i = 0; i < 8; i++) {
                    int q = tid + i * 256;           // u64 id 0..2047
                    int row = q >> 7, sb = (q & 127) * 8;
                    unsigned long long v = __hip_atomic_load(
                        reinterpret_cast<const unsigned long long*>(hb) + q,
                        __ATOMIC_RELAXED, __HIP_MEMORY_SCOPE_SYSTEM);
                    *reinterpret_cast<unsigned long long*>(
                        &Al[(row * 1024 + sb) ^ ((row & 7) << 4)]) = v;
                }
            }
        }
        __syncthreads();

        // 5. MFMA h-pass (W_hh half)
#pragma unroll
        for (int ks = 0; ks < 16; ++ks) {
            int kb = ks * 64 + kbhi;
            short8 a = *reinterpret_cast<const short8*>(&Al[(abase + kb) ^ axor]);
            short8 b = *reinterpret_cast<const short8*>(&Wl[(bbase + 1024 + kb) ^ bxor]);
            acc = __builtin_amdgcn_mfma_f32_16x16x32_bf16(a, b, acc, 0, 0, 0);
        }

        // 6. gate exchange via LDS
        {
            int col = w * 16 + (lane & 15);
            int rb  = (lane >> 4) * 4;
#pragma unroll
            for (int r = 0; r < 4; r++) Gl[rb + r][col] = acc[r];
        }
        __syncthreads();

        // 7. pointwise LSTM cell (thread owns (b_glob, u0+uu))
        float gi = Gl[bb][uu]      + bias_r[0];
        float gf = Gl[bb][16 + uu] + bias_r[1];
        float gg = Gl[bb][32 + uu] + bias_r[2];
        float go = Gl[bb][48 + uu] + bias_r[3];
        float iv = fsigmoid(gi), fv = fsigmoid(gf), gv = ftanh(gg), ov = fsigmoid(go);
        c_reg = fv * c_reg + iv * gv;
        float hv = ov * ftanh(c_reg);

        // 8. h store (packed dwords) + out store
        unsigned lo = (unsigned)bfbits(hv);
        unsigned hi = (unsigned)__shfl_down((int)lo, 1);
        if ((uu & 1) == 0) {
            unsigned* hw = reinterpret_cast<unsigned*>(
                hbuf + (size_t)((p ^ 1) * 2 + dir) * BATCH * HDIM) + ((b_glob * HDIM + u0 + uu) >> 1);
            unsigned val = lo | (hi << 16);
            if (fast) __hip_atomic_store(hw, val, __ATOMIC_RELAXED, __HIP_MEMORY_SCOPE_WORKGROUP);
            else      __hip_atomic_store(hw, val, __ATOMIC_RELAXED, __HIP_MEMORY_SCOPE_SYSTEM);
        }
        int tout = t;
        if (dir) tout = (t < Lb) ? (Lb - 1 - t) : t;
        out[((size_t)tout * BATCH + b_glob) * (2 * HDIM) + dir * HDIM + u0 + uu] = hv;

        __syncthreads();   // all waves' h stores drained (vmcnt(0) at barrier)
        if (tid == 0) {
            unsigned tok = (unsigned)(t + 1);
            if (fast) __hip_atomic_store(flagw, tok, __ATOMIC_RELAXED, __HIP_MEMORY_SCOPE_WORKGROUP);
            else      __hip_atomic_store(flagw, tok, __ATOMIC_RELAXED, __HIP_MEMORY_SCOPE_SYSTEM);
        }
    }

    cbuf[((size_t)dir * BATCH + b_glob) * HDIM + u0 + uu] = c_reg;
}

// ---------------------------------------------------------------------------
extern "C" void kernel_launch(void* const* d_in, const int* in_sizes, int n_in,
                              void* d_out, int out_size, void* d_ws, size_t ws_size,
                              hipStream_t stream)
{
    const float* x     = (const float*)d_in[0];
    const int* lengths = (const int*)d_in[1];
    const float* h0f   = (const float*)d_in[2];
    const float* c0f   = (const float*)d_in[3];
    const float* h0b   = (const float*)d_in[4];
    const float* c0b   = (const float*)d_in[5];
    const float* wihf  = (const float*)d_in[6];
    const float* whhf  = (const float*)d_in[7];
    const float* bihf  = (const float*)d_in[8];
    const float* bhhf  = (const float*)d_in[9];
    const float* wihb  = (const float*)d_in[10];
    const float* whhb  = (const float*)d_in[11];
    const float* bihb  = (const float*)d_in[12];
    const float* bhhb  = (const float*)d_in[13];
    float* out = (float*)d_out;

    char* ws = (char*)d_ws;
    bf16*     wih_bf = (bf16*)(ws);                        // 4 MB
    bf16*     whh_bf = (bf16*)(ws + (4u << 20));           // 4 MB
    float*    bias   = (float*)(ws + (8u << 20));          // 16 KB
    bf16*     hbuf   = (bf16*)(ws + (9u << 20));           // 256 KB
    float*    cbuf   = (float*)(ws + (10u << 20));         // 256 KB
    unsigned* flags  = (unsigned*)(ws + (11u << 20));      // 1 KB
    unsigned* xcdarr = (unsigned*)(ws + (11u << 20) + 4096);
    unsigned* abortw = (unsigned*)(ws + (11u << 20) + 8192);
    bf16*     xb     = (bf16*)(ws + (16u << 20));          // 64 MB

    conv_weights<<<dim3(2 * G4 * HDIM / 256), dim3(256), 0, stream>>>(
        wihf, whhf, bihf, bhhf, wihb, whhb, bihb, bhhb, wih_bf, whh_bf, bias);
    conv_x<<<dim3((T_LEN * BATCH * HDIM / 8) / 256), dim3(256), 0, stream>>>(x, xb);
    init_state<<<dim3(2 * BATCH * HDIM / 256), dim3(256), 0, stream>>>(
        h0f, c0f, h0b, c0b, hbuf, cbuf, flags, xcdarr, abortw);

    lstm_full<<<dim3(256), dim3(256), 0, stream>>>(
        xb, wih_bf, whh_bf, bias, lengths, hbuf, cbuf, out, flags, xcdarr, abortw);
}